// Round 1
// baseline (5224.514 us; speedup 1.0000x reference)
//
#include <hip/hip_runtime.h>
#include <stdint.h>

#define KT 500
#define KH 1024
#define KG 2048

typedef short bf16x8 __attribute__((ext_vector_type(8)));
typedef float f32x4 __attribute__((ext_vector_type(4)));

__device__ __forceinline__ unsigned short f2bf(float f){
  union { float f; unsigned int i; } u; u.f = f;
  unsigned int x = u.i;
  return (unsigned short)((x + 0x7fffu + ((x >> 16) & 1u)) >> 16);
}
__device__ __forceinline__ float bf2f(unsigned short h){
  union { unsigned int i; float f; } u; u.i = ((unsigned int)h) << 16;
  return u.f;
}

// device-scope (agent) 16B load / 4B store: sc1 => served at MALL coherence
// point, bypasses the non-coherent per-XCD L2.
template<int OFF>
__device__ __forceinline__ void load_b128_dev_off(uint4& dst, const void* p){
  asm volatile("global_load_dwordx4 %0, %1, off offset:%c2 sc1"
               : "=v"(dst) : "v"(p), "i"(OFF) : "memory");
}
__device__ __forceinline__ void store_b32_dev(void* p, unsigned int v){
  asm volatile("global_store_dword %0, %1, off sc1"
               :: "v"(p), "v"(v) : "memory");
}
__device__ __forceinline__ void wait_vm0(){
  asm volatile("s_waitcnt vmcnt(0)" ::: "memory");
}

// ---------------- cast fp32 -> bf16 (vectorized) ----------------
__global__ __launch_bounds__(256) void castk(const float* __restrict__ s,
                                             unsigned short* __restrict__ d, int n4){
  int i = blockIdx.x*256 + threadIdx.x;
  if (i >= n4) return;
  float4 v = ((const float4*)s)[i];
  unsigned int lo = (unsigned int)f2bf(v.x) | ((unsigned int)f2bf(v.y) << 16);
  unsigned int hi = (unsigned int)f2bf(v.z) | ((unsigned int)f2bf(v.w) << 16);
  ((uint2*)d)[i] = make_uint2(lo, hi);
}

// ---------------- 128x128 bf16 MFMA GEMM, x2/hcat indexing folded into A gather ---------
template<int MODE, int KDIM>
__global__ __launch_bounds__(256) void gemm_bn(
    const unsigned short* __restrict__ A,
    const unsigned short* __restrict__ Bw,   // [2048][KDIM] bf16 (gate-major)
    unsigned short* __restrict__ Wout)       // [16000][2048] bf16
{
  __shared__ __attribute__((aligned(16))) unsigned short As[128*72];
  __shared__ __attribute__((aligned(16))) unsigned short Bs[128*72];
  const int tid = threadIdx.x;
  const int lane = tid & 63, wid = tid >> 6;
  const int ntile = blockIdx.x, mtile = blockIdx.y;
  const int arow_loc = tid >> 3;   // 0..31
  const int k8 = tid & 7;

  long abaseLo[4], abaseHi[4], bbase[4];
  #pragma unroll
  for (int i = 0; i < 4; i++){
    int r = mtile*128 + i*32 + arow_loc;
    int s = r / KT;
    int t = r - s*KT;
    if (MODE == 0){
      abaseLo[i] = (s < 16) ? (long)((s*KT + t)*512)
                            : (long)(((s-16)*KT + (KT-1-t))*512);
      abaseHi[i] = 0;
    } else {
      int sp = s & 15;
      int rev = (s >= 16);
      abaseLo[i] = (long)((sp*KT + (rev ? KT-1-t : t)) * KH);
      abaseHi[i] = (long)(((16+sp)*KT + (rev ? t : KT-1-t)) * KH);
    }
    bbase[i] = (long)(ntile*128 + i*32 + arow_loc) * KDIM;
  }

  f32x4 acc[4][4];
  #pragma unroll
  for (int a=0;a<4;a++)
    #pragma unroll
    for (int b=0;b<4;b++)
      acc[a][b] = (f32x4){0.f,0.f,0.f,0.f};

  const int mhalf = wid & 1, nhalf = wid >> 1;
  const int lrow = lane & 15, quad = lane >> 4;

  for (int k0 = 0; k0 < KDIM; k0 += 64){
    const int kel = k0 + k8*8;
    #pragma unroll
    for (int i = 0; i < 4; i++){
      long aoff;
      if (MODE == 0) aoff = abaseLo[i] + kel;
      else           aoff = (kel < KH) ? (abaseLo[i] + kel) : (abaseHi[i] + (kel - KH));
      uint4 va = *(const uint4*)(A + aoff);
      uint4 vb = *(const uint4*)(Bw + bbase[i] + kel);
      *(uint4*)&As[(i*32 + arow_loc)*72 + k8*8] = va;
      *(uint4*)&Bs[(i*32 + arow_loc)*72 + k8*8] = vb;
    }
    __syncthreads();
    #pragma unroll
    for (int kk = 0; kk < 64; kk += 32){
      bf16x8 af[4], bfr[4];
      #pragma unroll
      for (int mt=0; mt<4; mt++)
        af[mt] = *(const bf16x8*)&As[(mhalf*64 + mt*16 + lrow)*72 + kk + quad*8];
      #pragma unroll
      for (int nt=0; nt<4; nt++)
        bfr[nt] = *(const bf16x8*)&Bs[(nhalf*64 + nt*16 + lrow)*72 + kk + quad*8];
      #pragma unroll
      for (int mt=0; mt<4; mt++)
        #pragma unroll
        for (int nt=0; nt<4; nt++)
          acc[mt][nt] = __builtin_amdgcn_mfma_f32_16x16x32_bf16(af[mt], bfr[nt], acc[mt][nt], 0, 0, 0);
    }
    __syncthreads();
  }

  #pragma unroll
  for (int mt=0; mt<4; mt++)
    #pragma unroll
    for (int nt=0; nt<4; nt++)
      #pragma unroll
      for (int r=0; r<4; r++){
        int grow = mtile*128 + mhalf*64 + mt*16 + quad*4 + r;
        int gcol = ntile*128 + nhalf*64 + nt*16 + lrow;
        Wout[(long)grow*KG + gcol] = f2bf(acc[mt][nt][r]);
      }
}

// ---------------- batchnorm stats ----------------
__global__ __launch_bounds__(256) void bn_partial(const unsigned short* __restrict__ W,
                                                  float* __restrict__ part){
  const int blk = blockIdx.x, tid = threadIdx.x;
  const int c0 = tid*8;
  float s[8], qq[8];
  #pragma unroll
  for (int j=0;j<8;j++){ s[j]=0.f; qq[j]=0.f; }
  const unsigned short* base = W + (long)blk*128*KG + c0;
  for (int r=0;r<128;r++){
    uint4 v = *(const uint4*)(base + (long)r*KG);
    unsigned int w[4] = {v.x, v.y, v.z, v.w};
    #pragma unroll
    for (int p=0;p<4;p++){
      union { unsigned int i; float f; } lo, hi;
      lo.i = w[p] << 16;
      hi.i = w[p] & 0xffff0000u;
      s[2*p]   += lo.f; qq[2*p]   += lo.f*lo.f;
      s[2*p+1] += hi.f; qq[2*p+1] += hi.f*hi.f;
    }
  }
  float* pd = part + (long)blk*4096;
  #pragma unroll
  for (int j=0;j<8;j++){ pd[c0+j] = s[j]; pd[KG + c0 + j] = qq[j]; }
}

__global__ __launch_bounds__(256) void bn_final(const float* __restrict__ part,
                                                const float* __restrict__ gamma,
                                                const float* __restrict__ beta,
                                                float* __restrict__ scsh){
  int g = blockIdx.x*256 + threadIdx.x;
  float s=0.f, qq=0.f;
  for (int b=0;b<125;b++){ s += part[(long)b*4096 + g]; qq += part[(long)b*4096 + KG + g]; }
  float mean = s * (1.f/16000.f);
  float var  = qq * (1.f/16000.f) - mean*mean;
  float sc = gamma[g] * rsqrtf(var + 1e-5f);
  scsh[g]      = sc;
  scsh[KG + g] = beta[g] - mean*sc;
}

// ---------------- persistent recurrence ----------------
// Block q owns h columns [16q,16q+16). 4 waves = (row-half m) x (K-half kh):
// each wave computes its 16 h-rows x all 32 gate cols over K=512 with the
// U slice held ENTIRELY IN REGISTERS (32x bf16x8 = 128 VGPR) and the h
// A-fragments loaded sc1 DIRECT from the MALL ping-pong into registers —
// no LDS on the matmul path at all. K-halves reduce through a tiny gA/gZ
// LDS buffer. h exchange protocol (sc1 stores + per-step flags) unchanged.
template<int LAYER>
__global__ __launch_bounds__(256, 1) void recur(
    const unsigned short* __restrict__ Ub,     // [2048][1024] bf16
    const unsigned short* __restrict__ Wn,     // [32][500][2048] bf16 (un-normalized)
    const float* __restrict__ scsh,            // [2][2048]
    unsigned short* __restrict__ hbuf,         // [2][32][1024] bf16 ping-pong (pre-zeroed)
    int* __restrict__ flags,                   // [500][64] (pre-zeroed)
    unsigned short* __restrict__ hsOut,        // LAYER 0: [32][500][1024] bf16
    float* __restrict__ out)                   // LAYER 1: [16][500][2048] fp32
{
  __shared__ float gA[32*20];   // stride 20: 2-way bank alias only (free)
  __shared__ float gZ[32*20];

  const int tid = threadIdx.x;
  const int q = blockIdx.x;
  const int ga = q*16;
  const int lane = tid & 63, wid = tid >> 6;
  const int lrow = lane & 15, quad = lane >> 4;
  const int m = wid & 1, kh = wid >> 1;     // row-half / K-half
  const int es = tid >> 3, ep = tid & 7;    // epilogue: row es, col pair 2ep

  // ---- U fragments -> registers (once). lane (lrow,quad) holds
  // U[gate_col = base+lrow][k = kh*512 + c*32 + quad*8 .. +8]
  bf16x8 ufA[16], ufZ[16];
  {
    const unsigned short* ua = Ub + (long)(ga + lrow)*KH + kh*512 + quad*8;
    const unsigned short* uz = ua + (long)KH*KH;
    #pragma unroll
    for (int c=0;c<16;c++){
      ufA[c] = *(const bf16x8*)(ua + c*32);
      ufZ[c] = *(const bf16x8*)(uz + c*32);
    }
  }

  // ---- per-thread epilogue constants (same thread reads+writes its own
  // h pair every step -> thread-private registers, no LDS)
  float2 scav = *(const float2*)&scsh[ga + 2*ep];
  float2 shav = *(const float2*)&scsh[KG + ga + 2*ep];
  float2 sczv = *(const float2*)&scsh[KH + ga + 2*ep];
  float2 shzv = *(const float2*)&scsh[KG + KH + ga + 2*ep];
  float2 hprev = make_float2(0.f, 0.f);

  const long aoff = (long)(m*16 + lrow)*KH + kh*512 + quad*8;
  const unsigned short* hb0 = hbuf + aoff;
  const unsigned short* hb1 = hbuf + 32768 + aoff;

  for (int t = 0; t < KT; t++){
    // prefetch w(t) (independent of h) before the poll; normal cached loads
    const unsigned short* wr = Wn + (long)(es*KT + t)*KG + ga + 2*ep;
    unsigned int wa01 = *(const unsigned int*)(wr);
    unsigned int wz01 = *(const unsigned int*)(wr + KH);
    asm volatile("" ::: "memory");

    // per-wave poll: K-half kh only needs producers [32kh, 32kh+32)
    if (t > 0){
      const int fl = (t-1)*64 + kh*32 + (lane & 31);
      while (__hip_atomic_load(&flags[fl], __ATOMIC_RELAXED,
                               __HIP_MEMORY_SCOPE_AGENT) == 0){}
    }

    // direct sc1 A-frag loads: 16 x 16B per lane, disjoint across waves
    const unsigned short* hb = (t & 1) ? hb1 : hb0;
    uint4 af[16];
    #define LDAF(i) load_b128_dev_off<(i)*64>(af[i], hb)
    LDAF(0);  LDAF(1);  LDAF(2);  LDAF(3);
    LDAF(4);  LDAF(5);  LDAF(6);  LDAF(7);
    LDAF(8);  LDAF(9);  LDAF(10); LDAF(11);
    LDAF(12); LDAF(13); LDAF(14); LDAF(15);
    #undef LDAF
    wait_vm0();
    __builtin_amdgcn_sched_barrier(0);   // rule #18: keep MFMAs below the wait

    f32x4 aA0 = (f32x4){0,0,0,0}, aA1 = aA0, aZ0 = aA0, aZ1 = aA0;
    #pragma unroll
    for (int c=0;c<16;c+=2){
      bf16x8 x0 = *(bf16x8*)&af[c];
      bf16x8 x1 = *(bf16x8*)&af[c+1];
      aA0 = __builtin_amdgcn_mfma_f32_16x16x32_bf16(x0, ufA[c],   aA0, 0,0,0);
      aZ0 = __builtin_amdgcn_mfma_f32_16x16x32_bf16(x0, ufZ[c],   aZ0, 0,0,0);
      aA1 = __builtin_amdgcn_mfma_f32_16x16x32_bf16(x1, ufA[c+1], aA1, 0,0,0);
      aZ1 = __builtin_amdgcn_mfma_f32_16x16x32_bf16(x1, ufZ[c+1], aZ1, 0,0,0);
    }
    f32x4 accA = aA0 + aA1;
    f32x4 accZ = aZ0 + aZ1;

    // K-half reduction: kh=1 writes, barrier, kh=0 read-add-writes
    if (kh){
      #pragma unroll
      for (int r=0;r<4;r++){
        gA[(m*16 + quad*4 + r)*20 + lrow] = accA[r];
        gZ[(m*16 + quad*4 + r)*20 + lrow] = accZ[r];
      }
    }
    __syncthreads();                                   // B2
    if (!kh){
      #pragma unroll
      for (int r=0;r<4;r++){
        int ix = (m*16 + quad*4 + r)*20 + lrow;
        gA[ix] += accA[r];
        gZ[ix] += accZ[r];
      }
    }
    __syncthreads();                                   // B3: gates ready

    // epilogue: one row, two adjacent cols per thread
    float2 gav = *(const float2*)&gA[es*20 + 2*ep];
    float2 gzv = *(const float2*)&gZ[es*20 + 2*ep];
    float aa0 = gav.x + bf2f((unsigned short)(wa01 & 0xffff)) * scav.x + shav.x;
    float aa1 = gav.y + bf2f((unsigned short)(wa01 >> 16))    * scav.y + shav.y;
    float zz0 = gzv.x + bf2f((unsigned short)(wz01 & 0xffff)) * sczv.x + shzv.x;
    float zz1 = gzv.y + bf2f((unsigned short)(wz01 >> 16))    * sczv.y + shzv.y;
    float z0 = 1.f/(1.f + __expf(-zz0));
    float z1 = 1.f/(1.f + __expf(-zz1));
    float hn0 = z0*hprev.x + (1.f - z0)*fmaxf(aa0, 0.f);
    float hn1 = z1*hprev.y + (1.f - z1)*fmaxf(aa1, 0.f);
    hprev = make_float2(hn0, hn1);

    unsigned int hpack = (unsigned int)f2bf(hn0) | ((unsigned int)f2bf(hn1) << 16);
    store_b32_dev(hbuf + ((t+1)&1)*32768 + es*KH + ga + 2*ep, hpack);
    wait_vm0();                                        // h at coherence point
    __syncthreads();                                   // B4: all waves drained
    if (tid == 0)
      __hip_atomic_store(&flags[t*64 + q], 1, __ATOMIC_RELAXED, __HIP_MEMORY_SCOPE_AGENT);

    // off-critical-path result stores (drained by next step / kernel end)
    if (LAYER == 0){
      *(unsigned int*)&hsOut[(long)(es*KT + t)*KH + ga + 2*ep] = hpack;
    } else {
      if (es < 16)
        *(float2*)&out[(long)(es*KT + t)*KG + ga + 2*ep] = make_float2(hn0, hn1);
      else
        *(float2*)&out[(long)((es-16)*KT + (KT-1-t))*KG + KH + ga + 2*ep] = make_float2(hn0, hn1);
    }
  }
}

// ---------------- orchestration ----------------
extern "C" void kernel_launch(void* const* d_in, const int* in_sizes, int n_in,
                              void* d_out, int out_size, void* d_ws, size_t ws_size,
                              hipStream_t stream)
{
  const float* x  = (const float*)d_in[0];
  const float* w0 = (const float*)d_in[1];
  const float* u0 = (const float*)d_in[2];
  const float* g0 = (const float*)d_in[3];
  const float* b0 = (const float*)d_in[4];
  const float* w1 = (const float*)d_in[5];
  const float* u1 = (const float*)d_in[6];
  const float* g1 = (const float*)d_in[7];
  const float* b1 = (const float*)d_in[8];
  float* out = (float*)d_out;

  char* p = (char*)d_ws;
  auto alloc = [&](size_t n){ char* r = p; p += (n + 255) & ~(size_t)255; return r; };
  unsigned short* xb   = (unsigned short*)alloc((size_t)16*KT*512*2);
  unsigned short* w0b  = (unsigned short*)alloc((size_t)KG*512*2);
  unsigned short* u0b  = (unsigned short*)alloc((size_t)KG*KH*2);
  unsigned short* w1b  = (unsigned short*)alloc((size_t)KG*KG*2);
  unsigned short* u1b  = (unsigned short*)alloc((size_t)KG*KH*2);
  unsigned short* wbuf = (unsigned short*)alloc((size_t)32*KT*KG*2);
  unsigned short* hs0  = (unsigned short*)alloc((size_t)32*KT*KH*2);
  float* part          = (float*)alloc((size_t)125*4096*4);
  float* scsh          = (float*)alloc((size_t)2*KG*4);
  unsigned short* hbuf = (unsigned short*)alloc((size_t)2*2*32*KH*2);
  int* flags           = (int*)alloc((size_t)2*KT*64*4);

  auto cast = [&](const float* s, unsigned short* d, int n){
    int n4 = n >> 2;
    castk<<<(n4+255)/256, 256, 0, stream>>>(s, d, n4);
  };
  cast(x,  xb,  16*KT*512);
  cast(w0, w0b, KG*512);
  cast(u0, u0b, KG*KH);
  cast(w1, w1b, KG*KG);
  cast(u1, u1b, KG*KH);
  hipMemsetAsync(hbuf,  0, (size_t)2*2*32*KH*2, stream);
  hipMemsetAsync(flags, 0, (size_t)2*KT*64*4,  stream);

  // layer 0
  gemm_bn<0,512><<<dim3(16,125), 256, 0, stream>>>(xb, w0b, wbuf);
  bn_partial<<<125,256,0,stream>>>(wbuf, part);
  bn_final<<<8,256,0,stream>>>(part, g0, b0, scsh);
  recur<0><<<64,256,0,stream>>>(u0b, wbuf, scsh, hbuf, flags, hs0, (float*)nullptr);

  // layer 1
  gemm_bn<1,2048><<<dim3(16,125), 256, 0, stream>>>(hs0, w1b, wbuf);
  bn_partial<<<125,256,0,stream>>>(wbuf, part);
  bn_final<<<8,256,0,stream>>>(part, g1, b1, scsh);
  recur<1><<<64,256,0,stream>>>(u1b, wbuf, scsh, hbuf + 2*32*KH, flags + KT*64,
                                (unsigned short*)nullptr, out);
}

// Round 3
// 4263.306 us; speedup vs baseline: 1.2255x; 1.2255x over previous
//
#include <hip/hip_runtime.h>
#include <stdint.h>

#define KT 500
#define KH 1024
#define KG 2048
#define FPAD 16   // each flag on its own 64B line

typedef short bf16x8 __attribute__((ext_vector_type(8)));
typedef float f32x4 __attribute__((ext_vector_type(4)));

__device__ __forceinline__ unsigned short f2bf(float f){
  union { float f; unsigned int i; } u; u.f = f;
  unsigned int x = u.i;
  return (unsigned short)((x + 0x7fffu + ((x >> 16) & 1u)) >> 16);
}
__device__ __forceinline__ float bf2f(unsigned short h){
  union { unsigned int i; float f; } u; u.i = ((unsigned int)h) << 16;
  return u.f;
}

// device-scope (agent) 16B load / 4B store: sc1 => served at MALL coherence
// point, bypasses the non-coherent per-XCD L2.
template<int OFF>
__device__ __forceinline__ void load_b128_dev_off(uint4& dst, const void* p){
  asm volatile("global_load_dwordx4 %0, %1, off offset:%c2 sc1"
               : "=v"(dst) : "v"(p), "i"(OFF) : "memory");
}
__device__ __forceinline__ void store_b32_dev(void* p, unsigned int v){
  asm volatile("global_store_dword %0, %1, off sc1"
               :: "v"(p), "v"(v) : "memory");
}
__device__ __forceinline__ void wait_vm0(){
  asm volatile("s_waitcnt vmcnt(0)" ::: "memory");
}
__device__ __forceinline__ void wait_vm8(){
  asm volatile("s_waitcnt vmcnt(8)" ::: "memory");
}

// ---------------- cast fp32 -> bf16 (vectorized) ----------------
__global__ __launch_bounds__(256) void castk(const float* __restrict__ s,
                                             unsigned short* __restrict__ d, int n4){
  int i = blockIdx.x*256 + threadIdx.x;
  if (i >= n4) return;
  float4 v = ((const float4*)s)[i];
  unsigned int lo = (unsigned int)f2bf(v.x) | ((unsigned int)f2bf(v.y) << 16);
  unsigned int hi = (unsigned int)f2bf(v.z) | ((unsigned int)f2bf(v.w) << 16);
  ((uint2*)d)[i] = make_uint2(lo, hi);
}

// ---------------- 128x128 bf16 MFMA GEMM, x2/hcat indexing folded into A gather ---------
template<int MODE, int KDIM>
__global__ __launch_bounds__(256) void gemm_bn(
    const unsigned short* __restrict__ A,
    const unsigned short* __restrict__ Bw,   // [2048][KDIM] bf16 (gate-major)
    unsigned short* __restrict__ Wout)       // [16000][2048] bf16
{
  __shared__ __attribute__((aligned(16))) unsigned short As[128*72];
  __shared__ __attribute__((aligned(16))) unsigned short Bs[128*72];
  const int tid = threadIdx.x;
  const int lane = tid & 63, wid = tid >> 6;
  const int ntile = blockIdx.x, mtile = blockIdx.y;
  const int arow_loc = tid >> 3;   // 0..31
  const int k8 = tid & 7;

  long abaseLo[4], abaseHi[4], bbase[4];
  #pragma unroll
  for (int i = 0; i < 4; i++){
    int r = mtile*128 + i*32 + arow_loc;
    int s = r / KT;
    int t = r - s*KT;
    if (MODE == 0){
      abaseLo[i] = (s < 16) ? (long)((s*KT + t)*512)
                            : (long)(((s-16)*KT + (KT-1-t))*512);
      abaseHi[i] = 0;
    } else {
      int sp = s & 15;
      int rev = (s >= 16);
      abaseLo[i] = (long)((sp*KT + (rev ? KT-1-t : t)) * KH);
      abaseHi[i] = (long)(((16+sp)*KT + (rev ? t : KT-1-t)) * KH);
    }
    bbase[i] = (long)(ntile*128 + i*32 + arow_loc) * KDIM;
  }

  f32x4 acc[4][4];
  #pragma unroll
  for (int a=0;a<4;a++)
    #pragma unroll
    for (int b=0;b<4;b++)
      acc[a][b] = (f32x4){0.f,0.f,0.f,0.f};

  const int mhalf = wid & 1, nhalf = wid >> 1;
  const int lrow = lane & 15, quad = lane >> 4;

  for (int k0 = 0; k0 < KDIM; k0 += 64){
    const int kel = k0 + k8*8;
    #pragma unroll
    for (int i = 0; i < 4; i++){
      long aoff;
      if (MODE == 0) aoff = abaseLo[i] + kel;
      else           aoff = (kel < KH) ? (abaseLo[i] + kel) : (abaseHi[i] + (kel - KH));
      uint4 va = *(const uint4*)(A + aoff);
      uint4 vb = *(const uint4*)(Bw + bbase[i] + kel);
      *(uint4*)&As[(i*32 + arow_loc)*72 + k8*8] = va;
      *(uint4*)&Bs[(i*32 + arow_loc)*72 + k8*8] = vb;
    }
    __syncthreads();
    #pragma unroll
    for (int kk = 0; kk < 64; kk += 32){
      bf16x8 af[4], bfr[4];
      #pragma unroll
      for (int mt=0; mt<4; mt++)
        af[mt] = *(const bf16x8*)&As[(mhalf*64 + mt*16 + lrow)*72 + kk + quad*8];
      #pragma unroll
      for (int nt=0; nt<4; nt++)
        bfr[nt] = *(const bf16x8*)&Bs[(nhalf*64 + nt*16 + lrow)*72 + kk + quad*8];
      #pragma unroll
      for (int mt=0; mt<4; mt++)
        #pragma unroll
        for (int nt=0; nt<4; nt++)
          acc[mt][nt] = __builtin_amdgcn_mfma_f32_16x16x32_bf16(af[mt], bfr[nt], acc[mt][nt], 0, 0, 0);
    }
    __syncthreads();
  }

  #pragma unroll
  for (int mt=0; mt<4; mt++)
    #pragma unroll
    for (int nt=0; nt<4; nt++)
      #pragma unroll
      for (int r=0; r<4; r++){
        int grow = mtile*128 + mhalf*64 + mt*16 + quad*4 + r;
        int gcol = ntile*128 + nhalf*64 + nt*16 + lrow;
        Wout[(long)grow*KG + gcol] = f2bf(acc[mt][nt][r]);
      }
}

// ---------------- batchnorm stats ----------------
__global__ __launch_bounds__(256) void bn_partial(const unsigned short* __restrict__ W,
                                                  float* __restrict__ part){
  const int blk = blockIdx.x, tid = threadIdx.x;
  const int c0 = tid*8;
  float s[8], qq[8];
  #pragma unroll
  for (int j=0;j<8;j++){ s[j]=0.f; qq[j]=0.f; }
  const unsigned short* base = W + (long)blk*128*KG + c0;
  for (int r=0;r<128;r++){
    uint4 v = *(const uint4*)(base + (long)r*KG);
    unsigned int w[4] = {v.x, v.y, v.z, v.w};
    #pragma unroll
    for (int p=0;p<4;p++){
      union { unsigned int i; float f; } lo, hi;
      lo.i = w[p] << 16;
      hi.i = w[p] & 0xffff0000u;
      s[2*p]   += lo.f; qq[2*p]   += lo.f*lo.f;
      s[2*p+1] += hi.f; qq[2*p+1] += hi.f*hi.f;
    }
  }
  float* pd = part + (long)blk*4096;
  #pragma unroll
  for (int j=0;j<8;j++){ pd[c0+j] = s[j]; pd[KG + c0 + j] = qq[j]; }
}

__global__ __launch_bounds__(256) void bn_final(const float* __restrict__ part,
                                                const float* __restrict__ gamma,
                                                const float* __restrict__ beta,
                                                float* __restrict__ scsh){
  int g = blockIdx.x*256 + threadIdx.x;
  float s=0.f, qq=0.f;
  for (int b=0;b<125;b++){ s += part[(long)b*4096 + g]; qq += part[(long)b*4096 + KG + g]; }
  float mean = s * (1.f/16000.f);
  float var  = qq * (1.f/16000.f) - mean*mean;
  float sc = gamma[g] * rsqrtf(var + 1e-5f);
  scsh[g]      = sc;
  scsh[KG + g] = beta[g] - mean*sc;
}

// ---------------- persistent recurrence ----------------
// Block q owns h columns [16q,16q+16). 4 waves = (row-half m) x (K-half kh):
// each wave computes its 16 h-rows x all 32 gate cols over K=512 with the
// U slice PINNED IN AGPRS (32x bf16x8 = 128 AGPR, forced via "+a" asm so it
// cannot spill) and the h A-fragments loaded sc1 DIRECT from the MALL
// ping-pong into registers. K-halves write DISJOINT LDS buffers; the
// epilogue adds them (single barrier). Flags are MONOTONIC (one padded
// 64B line per producer holding last-completed-step+1) -> 4KB total, no
// MALL-slice hotspot, no per-t array (stays inside the 128MB workspace).
template<int LAYER>
__global__ __launch_bounds__(256, 1) void recur(
    const unsigned short* __restrict__ Ub,     // [2048][1024] bf16
    const unsigned short* __restrict__ Wn,     // [32][500][2048] bf16 (un-normalized)
    const float* __restrict__ scsh,            // [2][2048]
    unsigned short* __restrict__ hbuf,         // [2][32][1024] bf16 ping-pong (pre-zeroed)
    int* __restrict__ flags,                   // [64][FPAD] (pre-zeroed)
    unsigned short* __restrict__ hsOut,        // LAYER 0: [32][500][1024] bf16
    float* __restrict__ out)                   // LAYER 1: [16][500][2048] fp32
{
  __shared__ float gA0[32*20];   // stride 20: 2-way bank alias only (free)
  __shared__ float gZ0[32*20];
  __shared__ float gA1[32*20];
  __shared__ float gZ1[32*20];

  const int tid = threadIdx.x;
  const int q = blockIdx.x;
  const int ga = q*16;
  const int lane = tid & 63, wid = tid >> 6;
  const int lrow = lane & 15, quad = lane >> 4;
  const int m = wid & 1, kh = wid >> 1;     // row-half / K-half
  const int es = tid >> 3, ep = tid & 7;    // epilogue: row es, col pair 2ep

  // ---- U fragments -> AGPRs (once). lane (lrow,quad) holds
  // U[gate_col = base+lrow][k = kh*512 + c*32 + quad*8 .. +8]
  bf16x8 ufA[16], ufZ[16];
  {
    const unsigned short* ua = Ub + (long)(ga + lrow)*KH + kh*512 + quad*8;
    const unsigned short* uz = ua + (long)KH*KH;
    #pragma unroll
    for (int c=0;c<16;c++){
      ufA[c] = *(const bf16x8*)(ua + c*32);
      asm volatile("" : "+a"(ufA[c]));    // pin to AGPR: no spill possible
      ufZ[c] = *(const bf16x8*)(uz + c*32);
      asm volatile("" : "+a"(ufZ[c]));
    }
  }

  // ---- per-thread epilogue constants (same thread reads+writes its own
  // h pair every step -> thread-private registers)
  float2 scav = *(const float2*)&scsh[ga + 2*ep];
  float2 shav = *(const float2*)&scsh[KG + ga + 2*ep];
  float2 sczv = *(const float2*)&scsh[KH + ga + 2*ep];
  float2 shzv = *(const float2*)&scsh[KG + KH + ga + 2*ep];
  float2 hprev = make_float2(0.f, 0.f);

  const long aoff = (long)(m*16 + lrow)*KH + kh*512 + quad*8;
  const unsigned short* hb0 = hbuf + aoff;
  const unsigned short* hb1 = hbuf + 32768 + aoff;

  for (int t = 0; t < KT; t++){
    // prefetch w(t) (independent of h) before the poll; normal cached loads
    const unsigned short* wr = Wn + (long)(es*KT + t)*KG + ga + 2*ep;
    unsigned int wa01 = *(const unsigned int*)(wr);
    unsigned int wz01 = *(const unsigned int*)(wr + KH);
    asm volatile("" ::: "memory");

    // per-wave poll: K-half kh needs producers [32kh, 32kh+32). Monotonic
    // flag: producer q holds (last completed step + 1); h(t) is ready when
    // flag >= t. Each flag on its own 64B line. The poll's internal waitcnt
    // also drains the w prefetch, so vmcnt is exact for the af loads below;
    // t==0 pre-drains explicitly.
    if (t > 0){
      if (lane < 32){
        const int* fp = &flags[(kh*32 + lane) << 4];
        while (__hip_atomic_load(fp, __ATOMIC_RELAXED,
                                 __HIP_MEMORY_SCOPE_AGENT) < t){}
      }
    } else {
      wait_vm0();
    }

    // direct sc1 A-frag loads: 16 x 16B per lane, disjoint across waves
    const unsigned short* hb = (t & 1) ? hb1 : hb0;
    uint4 af[16];
    #define LDAF(i) load_b128_dev_off<(i)*64>(af[i], hb)
    LDAF(0);  LDAF(1);  LDAF(2);  LDAF(3);
    LDAF(4);  LDAF(5);  LDAF(6);  LDAF(7);
    LDAF(8);  LDAF(9);  LDAF(10); LDAF(11);
    LDAF(12); LDAF(13); LDAF(14); LDAF(15);
    #undef LDAF

    f32x4 aA0 = (f32x4){0,0,0,0}, aA1 = aA0, aZ0 = aA0, aZ1 = aA0;

    wait_vm8();                          // af[0..7] resident
    __builtin_amdgcn_sched_barrier(0);   // rule #18
    #pragma unroll
    for (int c=0;c<8;c+=2){
      bf16x8 x0 = *(bf16x8*)&af[c];
      bf16x8 x1 = *(bf16x8*)&af[c+1];
      aA0 = __builtin_amdgcn_mfma_f32_16x16x32_bf16(x0, ufA[c],   aA0, 0,0,0);
      aZ0 = __builtin_amdgcn_mfma_f32_16x16x32_bf16(x0, ufZ[c],   aZ0, 0,0,0);
      aA1 = __builtin_amdgcn_mfma_f32_16x16x32_bf16(x1, ufA[c+1], aA1, 0,0,0);
      aZ1 = __builtin_amdgcn_mfma_f32_16x16x32_bf16(x1, ufZ[c+1], aZ1, 0,0,0);
    }
    wait_vm0();                          // af[8..15] resident
    __builtin_amdgcn_sched_barrier(0);
    #pragma unroll
    for (int c=8;c<16;c+=2){
      bf16x8 x0 = *(bf16x8*)&af[c];
      bf16x8 x1 = *(bf16x8*)&af[c+1];
      aA0 = __builtin_amdgcn_mfma_f32_16x16x32_bf16(x0, ufA[c],   aA0, 0,0,0);
      aZ0 = __builtin_amdgcn_mfma_f32_16x16x32_bf16(x0, ufZ[c],   aZ0, 0,0,0);
      aA1 = __builtin_amdgcn_mfma_f32_16x16x32_bf16(x1, ufA[c+1], aA1, 0,0,0);
      aZ1 = __builtin_amdgcn_mfma_f32_16x16x32_bf16(x1, ufZ[c+1], aZ1, 0,0,0);
    }
    f32x4 accA = aA0 + aA1;
    f32x4 accZ = aZ0 + aZ1;

    // K-halves write disjoint buffers; epilogue adds them -> ONE barrier
    {
      float* gAd = kh ? gA1 : gA0;
      float* gZd = kh ? gZ1 : gZ0;
      #pragma unroll
      for (int r=0;r<4;r++){
        gAd[(m*16 + quad*4 + r)*20 + lrow] = accA[r];
        gZd[(m*16 + quad*4 + r)*20 + lrow] = accZ[r];
      }
    }
    __syncthreads();                                   // B3: gates ready

    // epilogue: one row, two adjacent cols per thread
    float2 ga0 = *(const float2*)&gA0[es*20 + 2*ep];
    float2 ga1 = *(const float2*)&gA1[es*20 + 2*ep];
    float2 gz0 = *(const float2*)&gZ0[es*20 + 2*ep];
    float2 gz1 = *(const float2*)&gZ1[es*20 + 2*ep];
    float aa0 = ga0.x + ga1.x + bf2f((unsigned short)(wa01 & 0xffff)) * scav.x + shav.x;
    float aa1 = ga0.y + ga1.y + bf2f((unsigned short)(wa01 >> 16))    * scav.y + shav.y;
    float zz0 = gz0.x + gz1.x + bf2f((unsigned short)(wz01 & 0xffff)) * sczv.x + shzv.x;
    float zz1 = gz0.y + gz1.y + bf2f((unsigned short)(wz01 >> 16))    * sczv.y + shzv.y;
    float z0 = 1.f/(1.f + __expf(-zz0));
    float z1 = 1.f/(1.f + __expf(-zz1));
    float hn0 = z0*hprev.x + (1.f - z0)*fmaxf(aa0, 0.f);
    float hn1 = z1*hprev.y + (1.f - z1)*fmaxf(aa1, 0.f);
    hprev = make_float2(hn0, hn1);

    unsigned int hpack = (unsigned int)f2bf(hn0) | ((unsigned int)f2bf(hn1) << 16);

    // result stores FIRST (their acks drain together with the h store)
    if (LAYER == 0){
      *(unsigned int*)&hsOut[(long)(es*KT + t)*KH + ga + 2*ep] = hpack;
    } else {
      if (es < 16)
        *(float2*)&out[(long)(es*KT + t)*KG + ga + 2*ep] = make_float2(hn0, hn1);
      else
        *(float2*)&out[(long)((es-16)*KT + (KT-1-t))*KG + KH + ga + 2*ep] = make_float2(hn0, hn1);
    }

    store_b32_dev(hbuf + ((t+1)&1)*32768 + es*KH + ga + 2*ep, hpack);
    wait_vm0();                                        // h at coherence point
    __syncthreads();                                   // B4: all waves drained
    if (tid == 0)
      __hip_atomic_store(&flags[q << 4], t + 1, __ATOMIC_RELAXED,
                         __HIP_MEMORY_SCOPE_AGENT);
  }
}

// ---------------- orchestration ----------------
extern "C" void kernel_launch(void* const* d_in, const int* in_sizes, int n_in,
                              void* d_out, int out_size, void* d_ws, size_t ws_size,
                              hipStream_t stream)
{
  const float* x  = (const float*)d_in[0];
  const float* w0 = (const float*)d_in[1];
  const float* u0 = (const float*)d_in[2];
  const float* g0 = (const float*)d_in[3];
  const float* b0 = (const float*)d_in[4];
  const float* w1 = (const float*)d_in[5];
  const float* u1 = (const float*)d_in[6];
  const float* g1 = (const float*)d_in[7];
  const float* b1 = (const float*)d_in[8];
  float* out = (float*)d_out;

  char* p = (char*)d_ws;
  auto alloc = [&](size_t n){ char* r = p; p += (n + 255) & ~(size_t)255; return r; };
  unsigned short* xb   = (unsigned short*)alloc((size_t)16*KT*512*2);
  unsigned short* w0b  = (unsigned short*)alloc((size_t)KG*512*2);
  unsigned short* u0b  = (unsigned short*)alloc((size_t)KG*KH*2);
  unsigned short* w1b  = (unsigned short*)alloc((size_t)KG*KG*2);
  unsigned short* u1b  = (unsigned short*)alloc((size_t)KG*KH*2);
  unsigned short* wbuf = (unsigned short*)alloc((size_t)32*KT*KG*2);
  unsigned short* hs0  = (unsigned short*)alloc((size_t)32*KT*KH*2);
  float* part          = (float*)alloc((size_t)125*4096*4);
  float* scsh          = (float*)alloc((size_t)2*KG*4);
  unsigned short* hbuf = (unsigned short*)alloc((size_t)2*2*32*KH*2);
  int* flags           = (int*)alloc((size_t)2*64*FPAD*4);

  auto cast = [&](const float* s, unsigned short* d, int n){
    int n4 = n >> 2;
    castk<<<(n4+255)/256, 256, 0, stream>>>(s, d, n4);
  };
  cast(x,  xb,  16*KT*512);
  cast(w0, w0b, KG*512);
  cast(u0, u0b, KG*KH);
  cast(w1, w1b, KG*KG);
  cast(u1, u1b, KG*KH);
  hipMemsetAsync(hbuf,  0, (size_t)2*2*32*KH*2, stream);
  hipMemsetAsync(flags, 0, (size_t)2*64*FPAD*4, stream);

  // layer 0
  gemm_bn<0,512><<<dim3(16,125), 256, 0, stream>>>(xb, w0b, wbuf);
  bn_partial<<<125,256,0,stream>>>(wbuf, part);
  bn_final<<<8,256,0,stream>>>(part, g0, b0, scsh);
  recur<0><<<64,256,0,stream>>>(u0b, wbuf, scsh, hbuf, flags, hs0, (float*)nullptr);

  // layer 1
  gemm_bn<1,2048><<<dim3(16,125), 256, 0, stream>>>(hs0, w1b, wbuf);
  bn_partial<<<125,256,0,stream>>>(wbuf, part);
  bn_final<<<8,256,0,stream>>>(part, g1, b1, scsh);
  recur<1><<<64,256,0,stream>>>(u1b, wbuf, scsh, hbuf + 2*32*KH, flags + 64*FPAD,
                                (unsigned short*)nullptr, out);
}